// Round 11
// baseline (1756.450 us; speedup 1.0000x reference)
//
#include <hip/hip_runtime.h>

#define N_NODES 50000
#define HIDDEN 128
#define NUM_GRAPHS 64
#define NUM_CLASSES 6
#define SCAN_NB ((N_NODES + 255) / 256)   // 196
#define N_PAD 50048
#define DEG_STRIDE 16                     // one counter per 64B line
#define GRID_BLOCKS 1024                  // 4 blocks/CU x 256 CUs via __launch_bounds__(256,4)
#define NBAR 16

typedef __attribute__((ext_vector_type(8))) short short8;
typedef __attribute__((ext_vector_type(4))) float float4v;

__device__ __forceinline__ float b2f(unsigned short u) {
    return __uint_as_float(((unsigned)u) << 16);
}
__device__ __forceinline__ unsigned short f2b(float f) {
    unsigned u = __float_as_uint(f);
    return (unsigned short)((u + 0x7FFFu + ((u >> 16) & 1u)) >> 16);
}

struct Params {
    const float* x; const int* src; const int* dst; const int* batch;
    const float* W0; const float* b0; const float* W1; const float* b1;
    const float* W2; const float* b2; const float* linW; const float* linb;
    float* out;
    int* bar; int* off; int* deg; float* dinv; int* partial; int* rank; int* csr_col;
    unsigned short* xs; unsigned short* tb; unsigned short* hb; unsigned short* wb;
    float* emb; int* cnt;
    int E;
};

// software grid barrier: monotonic counter per instance (bar[] zeroed before launch)
__device__ __forceinline__ void gbar(int* bar, int idx) {
    __syncthreads();
    if (threadIdx.x == 0) {
        __threadfence();   // release: prior writes visible device-wide
        __hip_atomic_fetch_add(&bar[idx], 1, __ATOMIC_RELAXED, __HIP_MEMORY_SCOPE_AGENT);
        while (__hip_atomic_load(&bar[idx], __ATOMIC_RELAXED, __HIP_MEMORY_SCOPE_AGENT) < GRID_BLOCKS)
            __builtin_amdgcn_s_sleep(1);
        __threadfence();   // acquire: invalidate stale cached lines
    }
    __syncthreads();
}

// ---- agg: t[node] = dinv[node] * sum_p hs[csr_col[p]]  (wave per node, 8-deep gather ILP) ----
__device__ __forceinline__ void agg_phase(const unsigned short* __restrict__ hs,
                                          const int* __restrict__ off,
                                          const int* __restrict__ csr_col,
                                          const float* __restrict__ dinv,
                                          unsigned short* __restrict__ tb,
                                          int wid, int wstride, int lane) {
    const int grp = lane >> 4;
    const int fl = lane & 15;
    for (int node = wid; node < N_NODES; node += wstride) {
        const int p0 = off[node], p1 = off[node + 1];
        float acc[8];
#pragma unroll
        for (int j = 0; j < 8; j++) acc[j] = 0.f;
        for (int base = p0; base < p1; base += 64) {
            const int nb = min(64, p1 - base);
            const int nbm1 = nb - 1;
            int myc = (lane < nb) ? csr_col[base + lane] : 0;
            for (int c0 = 0; c0 < nb; c0 += 32) {
                int cc[8];
                float m[8];
#pragma unroll
                for (int k = 0; k < 8; k++) {
                    int e = c0 + k * 4 + grp;
                    m[k] = (e < nb) ? 1.f : 0.f;
                    cc[k] = __shfl(myc, min(e, nbm1), 64);
                }
                short8 u[8];
#pragma unroll
                for (int k = 0; k < 8; k++)
                    u[k] = *(const short8*)&hs[cc[k] * 128 + fl * 8];
#pragma unroll
                for (int k = 0; k < 8; k++)
#pragma unroll
                    for (int j = 0; j < 8; j++)
                        acc[j] += m[k] * b2f((unsigned short)u[k][j]);
            }
        }
#pragma unroll
        for (int j = 0; j < 8; j++) {
            acc[j] += __shfl_xor(acc[j], 16, 64);
            acc[j] += __shfl_xor(acc[j], 32, 64);
        }
        if (grp == 0) {
            const float dv = dinv[node];
            short8 o;
#pragma unroll
            for (int j = 0; j < 8; j++) o[j] = (short)f2b(acc[j] * dv);
            *(short8*)&tb[node * 128 + fl * 8] = o;
        }
    }
}

// ---- gemm: hout = [rowscale*] relu(tb @ W + b)  (wave per 16-row tile; N%16==0) ----
__device__ __forceinline__ void gemm_phase(const unsigned short* __restrict__ tb,
                                           const unsigned short* __restrict__ wb,
                                           const float* __restrict__ bias,
                                           const float* __restrict__ rowscale,
                                           unsigned short* __restrict__ hout,
                                           int wid, int wstride, int lane) {
    const int m = lane & 15;
    const int quad = lane >> 4;
    const short* B = (const short*)wb;
    const int ntile = N_NODES / 16;   // 3125
    for (int tile = wid; tile < ntile; tile += wstride) {
        const int r0 = tile * 16;
        const short* A = (const short*)tb;
        float4v acc[8];
#pragma unroll
        for (int nt = 0; nt < 8; nt++) acc[nt] = (float4v){0.f, 0.f, 0.f, 0.f};
#pragma unroll
        for (int ki = 0; ki < 4; ki++) {
            short8 a = *(const short8*)&A[(r0 + m) * 128 + ki * 32 + quad * 8];
#pragma unroll
            for (int nt = 0; nt < 8; nt++) {
                short8 b = *(const short8*)&B[((ki * 8 + nt) * 64 + lane) * 8];
                acc[nt] = __builtin_amdgcn_mfma_f32_16x16x32_bf16(a, b, acc[nt], 0, 0, 0);
            }
        }
        float sc[4];
#pragma unroll
        for (int reg = 0; reg < 4; reg++) {
            int row = r0 + quad * 4 + reg;
            sc[reg] = rowscale ? rowscale[row] : 1.f;
        }
#pragma unroll
        for (int nt = 0; nt < 8; nt++) {
            int c = nt * 16 + m;
            float bv = bias[c];
#pragma unroll
            for (int reg = 0; reg < 4; reg++) {
                int row = r0 + quad * 4 + reg;
                float v = fmaxf(acc[nt][reg] + bv, 0.f) * sc[reg];
                hout[row * 128 + c] = f2b(v);
            }
        }
    }
}

__global__ __launch_bounds__(256, 4) void mega(Params p) {
    __shared__ int sh_a[256];
    __shared__ int sh_b[256];

    const int t = threadIdx.x;
    const int lane = t & 63;
    const int gtid = blockIdx.x * 256 + t;
    const int gsz = GRID_BLOCKS * 256;
    const int wid = blockIdx.x * 4 + (t >> 6);
    const int wstride = GRID_BLOCKS * 4;
    const int E = p.E;
    int* bar = p.bar;

    // ---- P0: conv_w (weights -> MFMA-B fragment order) + count_deg (deg pre-zeroed by memset) ----
    for (int i = gtid; i < 3 * 16384; i += gsz) {
        int wsel = i >> 14;
        int r = i & 16383;
        int j = r & 7;
        int ln = (r >> 3) & 63;
        int f = r >> 9;
        int ki = f >> 3, nt = f & 7;
        int k = ki * 32 + (ln >> 4) * 8 + j;
        int c = nt * 16 + (ln & 15);
        const float* W = (wsel == 0) ? p.W0 : ((wsel == 1) ? p.W1 : p.W2);
        p.wb[i] = f2b(W[k * 128 + c]);
    }
    for (int i = gtid; i < E; i += gsz)
        p.rank[i] = atomicAdd(&p.deg[p.dst[i] * DEG_STRIDE], 1);
    gbar(bar, 0);

    // ---- P1: scan phase 1 (block sums) + dinv ----
    for (int vb = blockIdx.x; vb < SCAN_NB; vb += GRID_BLOCKS) {
        int i = vb * 256 + t;
        int dv = (i < N_NODES) ? (p.deg[i * DEG_STRIDE] + 1) : 0;
        if (i < N_NODES) p.dinv[i] = rsqrtf((float)dv);
        int v = dv;
        for (int d = 32; d > 0; d >>= 1) v += __shfl_down(v, d, 64);
        if ((t & 63) == 0) sh_a[t >> 6] = v;
        __syncthreads();
        if (t == 0) p.partial[vb] = sh_a[0] + sh_a[1] + sh_a[2] + sh_a[3];
        __syncthreads();
    }
    gbar(bar, 1);

    // ---- P2: scan phase 3 (folds partial-scan + self-entry) + cast_x (needs dinv only) ----
    for (int vb = blockIdx.x; vb < SCAN_NB; vb += GRID_BLOCKS) {
        int i = vb * 256 + t;
        int v = (i < N_NODES) ? (p.deg[i * DEG_STRIDE] + 1) : 0;
        sh_a[t] = v;
        sh_b[t] = (t < SCAN_NB) ? p.partial[t] : 0;
        __syncthreads();
        for (int d = 1; d < 256; d <<= 1) {
            int u1 = (t >= d) ? sh_a[t - d] : 0;
            int u2 = (t >= d) ? sh_b[t - d] : 0;
            __syncthreads();
            sh_a[t] += u1;
            sh_b[t] += u2;
            __syncthreads();
        }
        int base = (vb == 0) ? 0 : sh_b[vb - 1];
        if (i < N_NODES) {
            int pos = base + sh_a[t] - v;
            p.off[i] = pos;
            p.csr_col[pos] = i;
            if (i == N_NODES - 1) p.off[N_NODES] = base + sh_a[t];
        }
        __syncthreads();
    }
    for (int i4 = gtid; i4 < N_NODES * HIDDEN / 4; i4 += gsz) {
        int i = i4 * 4;
        float sc = p.dinv[i >> 7];
        float4 v = *(const float4*)&p.x[i];
        ushort4 o;
        o.x = f2b(v.x * sc); o.y = f2b(v.y * sc); o.z = f2b(v.z * sc); o.w = f2b(v.w * sc);
        *(ushort4*)&p.xs[i] = o;
    }
    gbar(bar, 2);

    // ---- P3: fill_edge (atomic-free; needs off + rank) ----
    for (int i = gtid; i < E; i += gsz) {
        int d = p.dst[i];
        int pos = p.off[d] + 1 + p.rank[i];
        p.csr_col[pos] = p.src[i];
    }
    gbar(bar, 3);

    // ---- layers ----
    agg_phase(p.xs, p.off, p.csr_col, p.dinv, p.tb, wid, wstride, lane);
    gbar(bar, 4);
    gemm_phase(p.tb, p.wb + 0 * 16384, p.b0, p.dinv, p.hb, wid, wstride, lane);
    gbar(bar, 5);
    agg_phase(p.hb, p.off, p.csr_col, p.dinv, p.tb, wid, wstride, lane);
    gbar(bar, 6);
    gemm_phase(p.tb, p.wb + 1 * 16384, p.b1, p.dinv, p.hb, wid, wstride, lane);
    gbar(bar, 7);
    agg_phase(p.hb, p.off, p.csr_col, p.dinv, p.tb, wid, wstride, lane);
    gbar(bar, 8);
    gemm_phase(p.tb, p.wb + 2 * 16384, p.b2, (const float*)nullptr, p.hb, wid, wstride, lane);
    gbar(bar, 9);

    // ---- P10: pooling (batch sorted); two 64-node halves per block ----
    {
        const int s2 = t >> 7;        // 0..1
        const int f = t & 127;
        const int nchunk = (N_NODES + 127) / 128;   // 391
        for (int vb = blockIdx.x; vb < nchunk; vb += GRID_BLOCKS) {
            int n0 = vb * 128 + s2 * 64;
            if (n0 < N_NODES) {
                int n1 = min(n0 + 64, N_NODES);
                float s = 0.f;
                int cloc = 0;
                int curg = p.batch[n0];
                for (int nn = n0; nn < n1; nn++) {
                    int g = p.batch[nn];
                    if (g != curg) {
                        atomicAdd(&p.emb[curg * HIDDEN + f], s);
                        if (f == 0) atomicAdd(&p.cnt[curg], cloc);
                        s = 0.f; cloc = 0; curg = g;
                    }
                    s += b2f(p.hb[nn * HIDDEN + f]);
                    cloc++;
                }
                atomicAdd(&p.emb[curg * HIDDEN + f], s);
                if (f == 0) atomicAdd(&p.cnt[curg], cloc);
            }
        }
    }
    gbar(bar, 10);

    // ---- P11: finalize ----
    {
        float* es = (float*)sh_a;
        for (int g = blockIdx.x; g < NUM_GRAPHS; g += GRID_BLOCKS) {
            if (t < 128) {
                float c = (float)max(p.cnt[g], 1);
                float e = p.emb[g * HIDDEN + t] / c;
                p.out[NUM_GRAPHS * NUM_CLASSES + g * HIDDEN + t] = e;
                es[t] = e;
            }
            __syncthreads();
            if (t < NUM_CLASSES) {
                float s = p.linb[t];
                for (int k = 0; k < HIDDEN; k++) s += es[k] * p.linW[k * NUM_CLASSES + t];
                p.out[g * NUM_CLASSES + t] = s;
            }
            __syncthreads();
        }
    }
}

extern "C" void kernel_launch(void* const* d_in, const int* in_sizes, int n_in,
                              void* d_out, int out_size, void* d_ws, size_t ws_size,
                              hipStream_t stream) {
    const int N = N_NODES;
    const int E = in_sizes[1] / 2;
    const int M = E + N;

    char* w = (char*)d_ws;
    size_t o = 0;
    auto alloc = [&](size_t bytes) { size_t r = o; o += (bytes + 255) & ~(size_t)255; return r; };
    // zeroed region first (one memset): bar, emb, cnt, deg
    int*            bar     = (int*)           (w + alloc((size_t)NBAR * 4));
    float*          emb     = (float*)         (w + alloc((size_t)NUM_GRAPHS * HIDDEN * 4));
    int*            cnt     = (int*)           (w + alloc((size_t)NUM_GRAPHS * 4));
    int*            deg     = (int*)           (w + alloc((size_t)N * DEG_STRIDE * 4));
    size_t zero_bytes = o;
    int*            off_i   = (int*)           (w + alloc((size_t)(N + 1) * 4));
    float*          dinv    = (float*)         (w + alloc((size_t)N * 4));
    int*            partial = (int*)           (w + alloc((size_t)SCAN_NB * 4));
    int*            rank    = (int*)           (w + alloc((size_t)E * 4));
    int*            csr_col = (int*)           (w + alloc((size_t)M * 4));
    unsigned short* xs      = (unsigned short*)(w + alloc((size_t)N_PAD * HIDDEN * 2));
    unsigned short* tb      = (unsigned short*)(w + alloc((size_t)N_PAD * HIDDEN * 2));
    unsigned short* hb      = (unsigned short*)(w + alloc((size_t)N_PAD * HIDDEN * 2));
    unsigned short* wb      = (unsigned short*)(w + alloc((size_t)3 * 16384 * 2));

    hipMemsetAsync(d_ws, 0, zero_bytes, stream);

    Params prm;
    prm.x    = (const float*)d_in[0];
    prm.src  = (const int*)d_in[1];
    prm.dst  = ((const int*)d_in[1]) + E;
    prm.batch= (const int*)d_in[2];
    prm.W0   = (const float*)d_in[3];
    prm.b0   = (const float*)d_in[4];
    prm.W1   = (const float*)d_in[5];
    prm.b1   = (const float*)d_in[6];
    prm.W2   = (const float*)d_in[7];
    prm.b2   = (const float*)d_in[8];
    prm.linW = (const float*)d_in[9];
    prm.linb = (const float*)d_in[10];
    prm.out  = (float*)d_out;
    prm.bar = bar; prm.off = off_i; prm.deg = deg; prm.dinv = dinv; prm.partial = partial;
    prm.rank = rank; prm.csr_col = csr_col;
    prm.xs = xs; prm.tb = tb; prm.hb = hb; prm.wb = wb;
    prm.emb = emb; prm.cnt = cnt;
    prm.E = E;

    mega<<<GRID_BLOCKS, 256, 0, stream>>>(prm);
}

// Round 12
// 293.135 us; speedup vs baseline: 5.9920x; 5.9920x over previous
//
#include <hip/hip_runtime.h>

#define N_NODES 50000
#define HIDDEN 128
#define NUM_GRAPHS 64
#define NUM_CLASSES 6
#define SCAN_NB ((N_NODES + 255) / 256)   // 196
#define N_PAD 50048
#define DEG_STRIDE 16                     // one counter per 64B line
#define CONV_BLOCKS 192                   // 3*16384/256
#define CASTX_BLOCKS ((N_NODES * HIDDEN / 4) / 256)  // 6250

typedef __attribute__((ext_vector_type(8))) short short8;
typedef __attribute__((ext_vector_type(4))) float float4v;
typedef __attribute__((ext_vector_type(2))) float float2v;

__device__ __forceinline__ float b2f(unsigned short u) {
    return __uint_as_float(((unsigned)u) << 16);
}
__device__ __forceinline__ unsigned short f2b(float f) {
    unsigned u = __float_as_uint(f);
    return (unsigned short)((u + 0x7FFFu + ((u >> 16) & 1u)) >> 16);
}
// fp8 e4m3 (OCP) encode via HW, RNE
__device__ __forceinline__ unsigned char f2e4m3(float f) {
    return (unsigned char)(__builtin_amdgcn_cvt_pk_fp8_f32(f, f, 0, false) & 0xFF);
}

// ---------------- prologue: conv_w (blocks [0,192)) + count_deg (rest) ----------------
__global__ __launch_bounds__(256) void prologue(const float* __restrict__ W0, const float* __restrict__ W1,
                                                const float* __restrict__ W2, unsigned short* __restrict__ wb,
                                                const int* __restrict__ dst, int* __restrict__ deg,
                                                int* __restrict__ rank, int e) {
    if (blockIdx.x < CONV_BLOCKS) {
        int i = blockIdx.x * 256 + threadIdx.x;   // < 3*16384 guaranteed
        int wsel = i >> 14;
        int r = i & 16383;
        int j = r & 7;
        int lane = (r >> 3) & 63;
        int f = r >> 9;               // 0..31
        int ki = f >> 3, nt = f & 7;
        int k = ki * 32 + (lane >> 4) * 8 + j;
        int c = nt * 16 + (lane & 15);
        const float* W = (wsel == 0) ? W0 : ((wsel == 1) ? W1 : W2);
        wb[i] = f2b(W[k * 128 + c]);
    } else {
        int i = (blockIdx.x - CONV_BLOCKS) * 256 + threadIdx.x;
        if (i < e) rank[i] = atomicAdd(&deg[dst[i] * DEG_STRIDE], 1);
    }
}

// ---------------- scan phase 1: block sums (+ dinv fold) ----------------
__global__ __launch_bounds__(256) void scan_b1(const int* __restrict__ deg, int* partial,
                                               float* __restrict__ dinv, int n) {
    __shared__ int red[4];
    const int t = threadIdx.x;
    const int i = blockIdx.x * 256 + t;
    int dv = (i < n) ? (deg[i * DEG_STRIDE] + 1) : 0;
    if (i < n) dinv[i] = rsqrtf((float)dv);
    int v = dv;
    for (int d = 32; d > 0; d >>= 1) v += __shfl_down(v, d, 64);
    if ((t & 63) == 0) red[t >> 6] = v;
    __syncthreads();
    if (t == 0) partial[blockIdx.x] = red[0] + red[1] + red[2] + red[3];
}

// ---------------- scan phase 3 (folds scan_b2 + self-entry) ----------------
__global__ __launch_bounds__(256) void scan_b3(const int* __restrict__ deg, const int* __restrict__ partial,
                                               int* off, int* __restrict__ csr_col, int n) {
    __shared__ int s[256];
    __shared__ int ps[256];
    const int t = threadIdx.x;
    const int b = blockIdx.x;
    const int i = b * 256 + t;
    int v = (i < n) ? (deg[i * DEG_STRIDE] + 1) : 0;
    s[t] = v;
    ps[t] = (t < SCAN_NB) ? partial[t] : 0;
    __syncthreads();
    for (int d = 1; d < 256; d <<= 1) {
        int u1 = (t >= d) ? s[t - d] : 0;
        int u2 = (t >= d) ? ps[t - d] : 0;
        __syncthreads();
        s[t] += u1;
        ps[t] += u2;
        __syncthreads();
    }
    int base = (b == 0) ? 0 : ps[b - 1];
    if (i < n) {
        int pos = base + s[t] - v;       // exclusive scan
        off[i] = pos;
        csr_col[pos] = i;                // self-loop first in segment
        if (i == n - 1) off[n] = base + s[t];
    }
}

// ---------------- mid: cast_x->fp8 (blocks [0,6250)) + fill_edge (rest) ----------------
__global__ __launch_bounds__(256) void midprep(const float* __restrict__ x, const float* __restrict__ dinv,
                                               unsigned char* __restrict__ xs8,
                                               const int* __restrict__ src, const int* __restrict__ dst,
                                               const int* __restrict__ rank, const int* __restrict__ off,
                                               int* __restrict__ csr_col, int e) {
    if (blockIdx.x < CASTX_BLOCKS) {
        int i = (blockIdx.x * 256 + threadIdx.x) * 4;   // < N*128 guaranteed
        float sc = dinv[i >> 7];
        float4 v = *(const float4*)&x[i];
        unsigned lo = __builtin_amdgcn_cvt_pk_fp8_f32(v.x * sc, v.y * sc, 0, false);
        unsigned pk = __builtin_amdgcn_cvt_pk_fp8_f32(v.z * sc, v.w * sc, lo, true);
        *(unsigned*)&xs8[i] = pk;
    } else {
        int i = (blockIdx.x - CASTX_BLOCKS) * 256 + threadIdx.x;
        if (i >= e) return;
        int d = dst[i];
        int pos = off[d] + 1 + rank[i];
        csr_col[pos] = src[i];
    }
}

// ---------------- aggregation: t[d] = dinv[d] * sum_p hs8[col[p]] (fp8 gather, f32 accum, bf16 out) ----------------
__global__ __launch_bounds__(256) void agg_fp8(const unsigned char* __restrict__ hs8, const int* __restrict__ off,
                                               const int* __restrict__ csr_col, const float* __restrict__ dinv,
                                               unsigned short* __restrict__ tb, int n) {
    const int wave = threadIdx.x >> 6;
    const int lane = threadIdx.x & 63;
    const int node = blockIdx.x * 4 + wave;
    if (node >= n) return;
    const int p0 = off[node], p1 = off[node + 1];
    const int grp = lane >> 4;      // 0..3: edge-in-chunk group
    const int fl = lane & 15;       // features fl*8 .. fl*8+7

    float acc[8];
#pragma unroll
    for (int j = 0; j < 8; j++) acc[j] = 0.f;

    for (int base = p0; base < p1; base += 64) {
        const int nb = min(64, p1 - base);
        const int nbm1 = nb - 1;
        int myc = (lane < nb) ? csr_col[base + lane] : 0;
        for (int c0 = 0; c0 < nb; c0 += 32) {
            int cc[8];
            float m[8];
#pragma unroll
            for (int k = 0; k < 8; k++) {
                int e = c0 + k * 4 + grp;
                m[k] = (e < nb) ? 1.f : 0.f;
                cc[k] = __shfl(myc, min(e, nbm1), 64);
            }
            uint2 u[8];
#pragma unroll
            for (int k = 0; k < 8; k++)
                u[k] = *(const uint2*)&hs8[cc[k] * 128 + fl * 8];
#pragma unroll
            for (int k = 0; k < 8; k++) {
                float2v f01 = __builtin_amdgcn_cvt_pk_f32_fp8(u[k].x, false);
                float2v f23 = __builtin_amdgcn_cvt_pk_f32_fp8(u[k].x, true);
                float2v f45 = __builtin_amdgcn_cvt_pk_f32_fp8(u[k].y, false);
                float2v f67 = __builtin_amdgcn_cvt_pk_f32_fp8(u[k].y, true);
                acc[0] += m[k] * f01.x;  acc[1] += m[k] * f01.y;
                acc[2] += m[k] * f23.x;  acc[3] += m[k] * f23.y;
                acc[4] += m[k] * f45.x;  acc[5] += m[k] * f45.y;
                acc[6] += m[k] * f67.x;  acc[7] += m[k] * f67.y;
            }
        }
    }

#pragma unroll
    for (int j = 0; j < 8; j++) {
        acc[j] += __shfl_xor(acc[j], 16, 64);
        acc[j] += __shfl_xor(acc[j], 32, 64);
    }

    if (grp == 0) {
        const float dv = dinv[node];
        short8 o;
#pragma unroll
        for (int j = 0; j < 8; j++) o[j] = (short)f2b(acc[j] * dv);
        *(short8*)&tb[node * 128 + fl * 8] = o;
    }
}

// ---------------- GEMM: out = [rowscale*] relu(t @ W + b); out fp8 (hout8) or bf16 (hout) ----------------
__global__ __launch_bounds__(256) void gemm_mfma(const unsigned short* __restrict__ tb,
                                                 const unsigned short* __restrict__ wb,
                                                 const float* __restrict__ bias,
                                                 const float* __restrict__ rowscale,
                                                 unsigned short* __restrict__ hout,
                                                 unsigned char* __restrict__ hout8, int n) {
    const int lane = threadIdx.x & 63;
    const int wave = threadIdx.x >> 6;
    const int r0 = blockIdx.x * 64 + wave * 16;
    const int m = lane & 15;
    const int quad = lane >> 4;
    const short* A = (const short*)tb;
    const short* B = (const short*)wb;

    float4v acc[8];
#pragma unroll
    for (int nt = 0; nt < 8; nt++) acc[nt] = (float4v){0.f, 0.f, 0.f, 0.f};

#pragma unroll
    for (int ki = 0; ki < 4; ki++) {
        short8 a = *(const short8*)&A[(r0 + m) * 128 + ki * 32 + quad * 8];
#pragma unroll
        for (int nt = 0; nt < 8; nt++) {
            short8 b = *(const short8*)&B[((ki * 8 + nt) * 64 + lane) * 8];
            acc[nt] = __builtin_amdgcn_mfma_f32_16x16x32_bf16(a, b, acc[nt], 0, 0, 0);
        }
    }

    float sc[4];
#pragma unroll
    for (int reg = 0; reg < 4; reg++) {
        int row = r0 + quad * 4 + reg;
        sc[reg] = (rowscale && row < n) ? rowscale[row] : 1.f;
    }

#pragma unroll
    for (int nt = 0; nt < 8; nt++) {
        int c = nt * 16 + m;
        float bv = bias[c];
#pragma unroll
        for (int reg = 0; reg < 4; reg++) {
            int row = r0 + quad * 4 + reg;
            if (row < n) {
                float v = fmaxf(acc[nt][reg] + bv, 0.f) * sc[reg];
                if (hout8) hout8[row * 128 + c] = f2e4m3(v);
                else       hout[row * 128 + c] = f2b(v);
            }
        }
    }
}

// ---------------- pooling (batch sorted), bf16 input ----------------
__global__ __launch_bounds__(128) void pool_kernel(const unsigned short* __restrict__ h, const int* __restrict__ batch,
                                                   float* emb, int* cnt, int n) {
    const int f = threadIdx.x;        // 0..127
    const int n0 = blockIdx.x * 64;
    const int n1 = min(n0 + 64, n);
    float s = 0.f;
    int cloc = 0;
    int curg = batch[n0];
    for (int nn = n0; nn < n1; nn++) {
        int g = batch[nn];
        if (g != curg) {
            atomicAdd(&emb[curg * HIDDEN + f], s);
            if (f == 0) atomicAdd(&cnt[curg], cloc);
            s = 0.f;
            cloc = 0;
            curg = g;
        }
        s += b2f(h[nn * HIDDEN + f]);
        cloc++;
    }
    atomicAdd(&emb[curg * HIDDEN + f], s);
    if (f == 0) atomicAdd(&cnt[curg], cloc);
}

// ---------------- finalize ----------------
__global__ __launch_bounds__(128) void finalize_kernel(const float* __restrict__ emb, const int* __restrict__ cnt,
                                                       const float* __restrict__ linW, const float* __restrict__ linb,
                                                       float* out) {
    const int g = blockIdx.x;
    const int f = threadIdx.x;
    __shared__ float es[128];
    float c = (float)max(cnt[g], 1);
    float e = emb[g * HIDDEN + f] / c;
    out[NUM_GRAPHS * NUM_CLASSES + g * HIDDEN + f] = e;
    es[f] = e;
    __syncthreads();
    if (f < NUM_CLASSES) {
        float s = linb[f];
        for (int k = 0; k < HIDDEN; k++) s += es[k] * linW[k * NUM_CLASSES + f];
        out[g * NUM_CLASSES + f] = s;
    }
}

extern "C" void kernel_launch(void* const* d_in, const int* in_sizes, int n_in,
                              void* d_out, int out_size, void* d_ws, size_t ws_size,
                              hipStream_t stream) {
    const float* x    = (const float*)d_in[0];
    const int*   ei   = (const int*)d_in[1];
    const int*   batch= (const int*)d_in[2];
    const float* W0   = (const float*)d_in[3];
    const float* b0   = (const float*)d_in[4];
    const float* W1   = (const float*)d_in[5];
    const float* b1   = (const float*)d_in[6];
    const float* W2   = (const float*)d_in[7];
    const float* b2   = (const float*)d_in[8];
    const float* linW = (const float*)d_in[9];
    const float* linb = (const float*)d_in[10];
    float* out = (float*)d_out;

    const int N = N_NODES;
    const int E = in_sizes[1] / 2;
    const int M = E + N;
    const int* srcp = ei;
    const int* dstp = ei + E;

    char* w = (char*)d_ws;
    size_t o = 0;
    auto alloc = [&](size_t bytes) { size_t r = o; o += (bytes + 255) & ~(size_t)255; return r; };
    int*            off_i   = (int*)           (w + alloc((size_t)(N + 1) * 4));
    int*            deg     = (int*)           (w + alloc((size_t)N * DEG_STRIDE * 4));
    float*          dinv    = (float*)         (w + alloc((size_t)N * 4));
    int*            partial = (int*)           (w + alloc((size_t)SCAN_NB * 4));
    int*            rank    = (int*)           (w + alloc((size_t)E * 4));
    int*            csr_col = (int*)           (w + alloc((size_t)M * 4));
    unsigned char*  xs8     = (unsigned char*) (w + alloc((size_t)N_PAD * HIDDEN));
    unsigned char*  h8      = (unsigned char*) (w + alloc((size_t)N_PAD * HIDDEN));
    unsigned short* tb      = (unsigned short*)(w + alloc((size_t)N_PAD * HIDDEN * 2));
    unsigned short* hb      = (unsigned short*)(w + alloc((size_t)N_PAD * HIDDEN * 2));
    unsigned short* wb      = (unsigned short*)(w + alloc((size_t)3 * 16384 * 2));
    float*          emb     = (float*)         (w + alloc((size_t)NUM_GRAPHS * HIDDEN * 4));
    int*            cnt     = (int*)           (w + alloc((size_t)NUM_GRAPHS * 4));

    hipMemsetAsync(deg, 0, (size_t)N * DEG_STRIDE * 4, stream);
    hipMemsetAsync(emb, 0, (size_t)(NUM_GRAPHS * HIDDEN * 4 + 256 + NUM_GRAPHS * 4), stream); // emb + pad + cnt

    const int edge_blocks = (E + 255) / 256;

    prologue<<<CONV_BLOCKS + edge_blocks, 256, 0, stream>>>(W0, W1, W2, wb, dstp, deg, rank, E);

    scan_b1<<<SCAN_NB, 256, 0, stream>>>(deg, partial, dinv, N);
    scan_b3<<<SCAN_NB, 256, 0, stream>>>(deg, partial, off_i, csr_col, N);

    midprep<<<CASTX_BLOCKS + edge_blocks, 256, 0, stream>>>(x, dinv, xs8, srcp, dstp, rank, off_i, csr_col, E);

    const int gemm_grid = (N + 63) / 64;   // 782
    const int agg_grid  = (N + 3) / 4;     // 12500

    // layer 0
    agg_fp8<<<agg_grid, 256, 0, stream>>>(xs8, off_i, csr_col, dinv, tb, N);
    gemm_mfma<<<gemm_grid, 256, 0, stream>>>(tb, wb + 0 * 16384, b0, dinv, (unsigned short*)nullptr, h8, N);
    // layer 1
    agg_fp8<<<agg_grid, 256, 0, stream>>>(h8, off_i, csr_col, dinv, tb, N);
    gemm_mfma<<<gemm_grid, 256, 0, stream>>>(tb, wb + 1 * 16384, b1, dinv, (unsigned short*)nullptr, h8, N);
    // layer 2 (bf16 out for pooling)
    agg_fp8<<<agg_grid, 256, 0, stream>>>(h8, off_i, csr_col, dinv, tb, N);
    gemm_mfma<<<gemm_grid, 256, 0, stream>>>(tb, wb + 2 * 16384, b2, (const float*)nullptr, hb, (unsigned char*)nullptr, N);

    pool_kernel<<<(N + 63) / 64, 128, 0, stream>>>(hb, batch, emb, cnt, N);
    finalize_kernel<<<NUM_GRAPHS, 128, 0, stream>>>(emb, cnt, linW, linb, out);
}